// Round 9
// baseline (2047.404 us; speedup 1.0000x reference)
//
#include <hip/hip_runtime.h>
#include <hip/hip_bf16.h>

typedef float f32x4 __attribute__((ext_vector_type(4)));
typedef __bf16 bf16x8 __attribute__((ext_vector_type(8)));
typedef unsigned short u16x8 __attribute__((ext_vector_type(8)));
typedef unsigned short u16x4 __attribute__((ext_vector_type(4)));
typedef unsigned short u16;

// LDS map (dynamic, 40512 B -> 2 blocks/CU; VGPR (cap 128) is the occupancy limit):
//   z    @ 0      32768  [32][512] bf16, XOR-swizzled rows
//   nrm  @ 32768   1024  [32][16] bf16
//   h    @ 33792   4608  [32][72] bf16
//   scl  @ 38400   2048  [32][16] f32
//   gate @ 40448     64  [16] f32
//   enc1 x-stage (4 KB, [32][64] bf16) overlays nrm+h (dead during enc1)
#define SMEM_BYTES 40512
#define Z_OFF 0
#define NRM_OFF 32768
#define H_OFF 33792
#define SCL_OFF 38400
#define GATE_OFF 40448

__device__ __forceinline__ u16 f2bf(float f) {        // native cvt (RNE)
  __bf16 h = (__bf16)f;
  return __builtin_bit_cast(u16, h);
}
__device__ __forceinline__ float bf2f(u16 s) {
  return __uint_as_float(((unsigned int)s) << 16);
}
__device__ __forceinline__ float gelu_f(float x) {
  return 0.5f * x * (1.0f + erff(x * 0.70710678118654752f)); // erf GELU
}
#define MFMA(a, b, c) __builtin_amdgcn_mfma_f32_16x16x32_bf16((a), (b), (c), 0, 0, 0)

// ---------------- merged weight conversion ----------------
__global__ void cvt_all(const float* __restrict__ e1, const float* __restrict__ e2,
                        const float* __restrict__ e3, const float* __restrict__ d1,
                        const float* __restrict__ d2, const float* __restrict__ d3,
                        const float* __restrict__ mx, u16* __restrict__ dst)
{
  int i = blockIdx.x * blockDim.x + threadIdx.x;
  int stride = gridDim.x * blockDim.x;
  for (; i < 3145728; i += stride) {
    float v;
    if (i < 524288)        v = e1[i];
    else if (i < 786432)   v = e2[i - 524288];
    else if (i < 1048576)  v = e3[i - 786432];
    else if (i < 1310720)  v = d1[i - 1048576];
    else if (i < 1572864)  v = d2[i - 1310720];
    else if (i < 2097152)  v = d3[i - 1572864];
    else {
      // mix_w [L,16,16,32,32] (l,bi,j,e,d) -> W[l][o=bi*32+e][k=j*32+d]
      int j = i - 2097152;
      int l = j >> 18, rem = j & 262143;
      int o = rem >> 9, k = rem & 511;
      int bi = o >> 5, e = o & 31, jj = k >> 5, dd = k & 31;
      v = mx[(((l * 16 + bi) * 16 + jj) * 32 + e) * 32 + dd];
    }
    dst[i] = f2bf(v);
  }
}

// ---------------- in-place strip GEMM: z(32x512) x W^T ----------------
// 8 waves; wave wid owns cols [wid*64, wid*64+64): acc[2][4] = 32 VGPR.
// K-loop barrier-free: A from LDS, B double-buffered global->VGPR (L2-resident).
// EPI: 0 gelu+bias->z ; 1 bias->z ; 2 latent combine->z ; 3 bias->f32 global
template<int EPI>
__device__ __forceinline__ void gemm512(char* __restrict__ smem,
    const u16* __restrict__ W, const float* __restrict__ bias,
    float* __restrict__ outG, int nOff, int m0)
{
  __syncthreads();                       // previous phase's z writes visible
  const int tid = threadIdx.x;
  const int lane = tid & 63;
  const int wid = tid >> 6;
  const int c0 = wid << 6;
  const int r16 = lane & 15;
  const int kg2 = (lane >> 4) << 4;      // byte k-offset within 64B k-step
  const int sw = (r16 & 7) << 4;
  char* z = smem + Z_OFF;
  const char* za = z + r16 * 1024;

  const u16* p0 = W + (size_t)(nOff + c0 +  0 + r16) * 512 + (kg2 >> 1);
  const u16* p1 = W + (size_t)(nOff + c0 + 16 + r16) * 512 + (kg2 >> 1);
  const u16* p2 = W + (size_t)(nOff + c0 + 32 + r16) * 512 + (kg2 >> 1);
  const u16* p3 = W + (size_t)(nOff + c0 + 48 + r16) * 512 + (kg2 >> 1);

  f32x4 acc[2][4] = {};
  bf16x8 bc0 = *(const bf16x8*)p0, bc1 = *(const bf16x8*)p1;
  bf16x8 bc2 = *(const bf16x8*)p2, bc3 = *(const bf16x8*)p3;

  #pragma unroll 1
  for (int ks2 = 0; ks2 < 8; ++ks2) {
    // ---- even k-step: compute with bc, prefetch bn (+64B) ----
    bf16x8 bn0, bn1, bn2, bn3;
    bn0 = *(const bf16x8*)(p0 + 32); bn1 = *(const bf16x8*)(p1 + 32);
    bn2 = *(const bf16x8*)(p2 + 32); bn3 = *(const bf16x8*)(p3 + 32);
    {
      const int ka = ((ks2 << 7) | kg2) ^ sw;
      bf16x8 a0 = *(const bf16x8*)(za + ka);
      bf16x8 a1 = *(const bf16x8*)(za + 16384 + ka);
      __builtin_amdgcn_s_setprio(1);
      acc[0][0] = MFMA(a0, bc0, acc[0][0]); acc[0][1] = MFMA(a0, bc1, acc[0][1]);
      acc[0][2] = MFMA(a0, bc2, acc[0][2]); acc[0][3] = MFMA(a0, bc3, acc[0][3]);
      acc[1][0] = MFMA(a1, bc0, acc[1][0]); acc[1][1] = MFMA(a1, bc1, acc[1][1]);
      acc[1][2] = MFMA(a1, bc2, acc[1][2]); acc[1][3] = MFMA(a1, bc3, acc[1][3]);
      __builtin_amdgcn_s_setprio(0);
    }
    // ---- odd k-step: compute with bn, prefetch bc for next iter (+128B) ----
    if (ks2 < 7) {
      bc0 = *(const bf16x8*)(p0 + 64); bc1 = *(const bf16x8*)(p1 + 64);
      bc2 = *(const bf16x8*)(p2 + 64); bc3 = *(const bf16x8*)(p3 + 64);
    }
    {
      const int kb = ((ks2 << 7) | 64 | kg2) ^ sw;
      bf16x8 a0 = *(const bf16x8*)(za + kb);
      bf16x8 a1 = *(const bf16x8*)(za + 16384 + kb);
      __builtin_amdgcn_s_setprio(1);
      acc[0][0] = MFMA(a0, bn0, acc[0][0]); acc[0][1] = MFMA(a0, bn1, acc[0][1]);
      acc[0][2] = MFMA(a0, bn2, acc[0][2]); acc[0][3] = MFMA(a0, bn3, acc[0][3]);
      acc[1][0] = MFMA(a1, bn0, acc[1][0]); acc[1][1] = MFMA(a1, bn1, acc[1][1]);
      acc[1][2] = MFMA(a1, bn2, acc[1][2]); acc[1][3] = MFMA(a1, bn3, acc[1][3]);
      __builtin_amdgcn_s_setprio(0);
    }
    p0 += 64; p1 += 64; p2 += 64; p3 += 64;
  }

  __syncthreads();                       // all waves done reading z

  const float* scl = (const float*)(smem + SCL_OFF);
  const float* gateL = (const float*)(smem + GATE_OFF);
  #pragma unroll
  for (int nt = 0; nt < 4; ++nt) {
    const int col = c0 + nt * 16 + r16;
    float bv_ = 0.f, gate = 0.f;
    if constexpr (EPI == 0 || EPI == 1 || EPI == 3) bv_ = bias[nOff + col];
    if constexpr (EPI == 2) gate = gateL[col >> 5];
    #pragma unroll
    for (int mt = 0; mt < 2; ++mt) {
      #pragma unroll
      for (int r = 0; r < 4; ++r) {
        const int row = mt * 16 + ((lane >> 4) << 2) + r;
        float v = acc[mt][nt][r];
        if constexpr (EPI == 3) {
          outG[(size_t)(m0 + row) * 1024 + nOff + col] = v + bv_;
        } else {
          char* zp = z + row * 1024 + ((col << 1) ^ ((row & 7) << 4));
          if constexpr (EPI == 0)      *(u16*)zp = f2bf(gelu_f(v + bv_));
          else if constexpr (EPI == 1) *(u16*)zp = f2bf(v + bv_);
          else {
            float sc = scl[row * 16 + (col >> 5)];
            float zo = bf2f(*(const u16*)zp);
            *(u16*)zp = f2bf(zo * (1.f + sc) + gate * v);
          }
        }
      }
    }
  }
}

// ---------------- bundle norms -> MLP -> softplus scales (+gates) ----------------
__device__ __forceinline__ void norm_phase(char* __restrict__ smem,
    const float* __restrict__ w1, const float* __restrict__ b1,
    const float* __restrict__ w2, const float* __restrict__ b2,
    const float* __restrict__ w3, const float* __restrict__ gb)
{
  __syncthreads();
  const int tid = threadIdx.x;
  const int lane = tid & 63;
  const int wv = tid >> 6;
  u16* nrmb = (u16*)(smem + NRM_OFF);      // [32][16] bf16
  u16* h    = (u16*)(smem + H_OFF);        // [32][72] bf16
  float* scl = (float*)(smem + SCL_OFF);
  float* gateL = (float*)(smem + GATE_OFF);
  const char* z = smem + Z_OFF;

  // N1: one wave per row; lane L holds elems [8L,8L+8) -> bundle = L>>2
  #pragma unroll
  for (int p = 0; p < 4; ++p) {
    const int row = p * 8 + wv;
    u16x8 v = *(const u16x8*)(z + row * 1024 + ((lane << 4) ^ ((row & 7) << 4)));
    float ss = 0.f;
    #pragma unroll
    for (int j = 0; j < 8; ++j) { float f = bf2f(v[j]); ss += f * f; }
    ss += __shfl_xor(ss, 1);
    ss += __shfl_xor(ss, 2);
    if ((lane & 3) == 0) nrmb[row * 16 + (lane >> 2)] = f2bf(sqrtf(ss) + 1e-8f);
  }
  if (tid < 16) gateL[tid] = 1.f / (1.f + expf(-gb[tid]));
  __syncthreads();

  // N2: wave wv owns rows wv*4..wv*4+3; lane j computes h1[row][j]
  {
    const float4* w1r = (const float4*)(w1 + lane * 16);
    float a[4];
    #pragma unroll
    for (int p = 0; p < 4; ++p) a[p] = b1[lane];
    #pragma unroll
    for (int q = 0; q < 4; ++q) {
      float4 wv4 = w1r[q];
      #pragma unroll
      for (int t = 0; t < 4; ++t) {
        const int i = q * 4 + t;
        const float w = ((const float*)&wv4)[t];
        #pragma unroll
        for (int p = 0; p < 4; ++p)
          a[p] += bf2f(nrmb[(wv * 4 + p) * 16 + i]) * w;
      }
    }
    #pragma unroll
    for (int p = 0; p < 4; ++p) h[(wv * 4 + p) * 72 + lane] = f2bf(gelu_f(a[p]));
  }
  __syncthreads();
  // N3: h = gelu(h @ w2^T + b2); rows wave-local, vectorized h reads
  {
    float a[4];
    #pragma unroll
    for (int p = 0; p < 4; ++p) a[p] = b2[lane];
    const float4* w2r = (const float4*)(w2 + lane * 64);
    #pragma unroll
    for (int k8 = 0; k8 < 8; ++k8) {
      float4 wA = w2r[k8 * 2], wB = w2r[k8 * 2 + 1];
      #pragma unroll
      for (int p = 0; p < 4; ++p) {
        u16x8 hv = *(const u16x8*)(h + (wv * 4 + p) * 72 + k8 * 8);
        a[p] += bf2f(hv[0]) * wA.x + bf2f(hv[1]) * wA.y + bf2f(hv[2]) * wA.z + bf2f(hv[3]) * wA.w
              + bf2f(hv[4]) * wB.x + bf2f(hv[5]) * wB.y + bf2f(hv[6]) * wB.z + bf2f(hv[7]) * wB.w;
      }
    }
    // wave-local rows: reads precede writes within the wave
    #pragma unroll
    for (int p = 0; p < 4; ++p) h[(wv * 4 + p) * 72 + lane] = f2bf(gelu_f(a[p]));
  }
  __syncthreads();
  // N4: scl = softplus(h2 @ w3^T): 32 rows x 16 bundles, one per thread
  {
    const int b = tid & 15;
    const int r0 = tid >> 4;               // 0..31
    const float4* w3r = (const float4*)(w3 + b * 64);
    float a0 = 0.f;
    #pragma unroll
    for (int k8 = 0; k8 < 8; ++k8) {
      float4 wA = w3r[k8 * 2], wB = w3r[k8 * 2 + 1];
      u16x8 h0 = *(const u16x8*)(h + r0 * 72 + k8 * 8);
      a0 += bf2f(h0[0]) * wA.x + bf2f(h0[1]) * wA.y + bf2f(h0[2]) * wA.z + bf2f(h0[3]) * wA.w
          + bf2f(h0[4]) * wB.x + bf2f(h0[5]) * wB.y + bf2f(h0[6]) * wB.z + bf2f(h0[7]) * wB.w;
    }
    a0 = (a0 > 20.f) ? a0 : log1pf(expf(a0));
    scl[r0 * 16 + b] = a0;
  }
  __syncthreads();
}

// ---------------- fused network: one block per 32-row strip ----------------
// (512,2) -> VGPR cap 128 (empirical: cap = 256/min_waves). Live set ~90.
__global__ __launch_bounds__(512, 2)
void ugn_mega(const float* __restrict__ x,
              const float* __restrict__ enc_b1, const float* __restrict__ enc_b2,
              const float* __restrict__ enc_b3,
              const float* __restrict__ mlp1_w, const float* __restrict__ mlp1_b,
              const float* __restrict__ mlp2_w, const float* __restrict__ mlp2_b,
              const float* __restrict__ mlp3_w, const float* __restrict__ gate_b,
              const float* __restrict__ dec_b1, const float* __restrict__ dec_b2,
              const float* __restrict__ dec_b3,
              const u16* __restrict__ wE1, const u16* __restrict__ wE2,
              const u16* __restrict__ wE3, const u16* __restrict__ wMix,
              const u16* __restrict__ wD1, const u16* __restrict__ wD2,
              const u16* __restrict__ wD3, float* __restrict__ out)
{
  extern __shared__ char smem[];
  const int m0 = blockIdx.x << 5;          // 32-row strip
  const int tid = threadIdx.x;
  const int lane = tid & 63;
  const int wid = tid >> 6;
  const int c0 = wid << 6;
  const int r16 = lane & 15;
  const int kg2 = (lane >> 4) << 4;
  const int sw = (r16 & 7) << 4;

  // ===== enc1: z = gelu(x @ wE1^T + b1), K=1024 in 16 LDS-staged chunks =====
  {
    char* stage = smem + NRM_OFF;          // 4KB [32][64] bf16 swizzled
    char* z = smem + Z_OFF;
    const float* xs = x + (size_t)m0 * 1024;
    const int xr = tid >> 4;               // 0..31
    const int kp4 = (tid & 15) << 2;       // f32 idx 0..60 within chunk
    const u16* q0 = wE1 + (size_t)(c0 +  0 + r16) * 1024 + (kg2 >> 1);
    const u16* q1 = wE1 + (size_t)(c0 + 16 + r16) * 1024 + (kg2 >> 1);
    const u16* q2 = wE1 + (size_t)(c0 + 32 + r16) * 1024 + (kg2 >> 1);
    const u16* q3 = wE1 + (size_t)(c0 + 48 + r16) * 1024 + (kg2 >> 1);

    float4 v = *(const float4*)(xs + (size_t)xr * 1024 + kp4);
    f32x4 acc[2][4] = {};
    #pragma unroll 1
    for (int c = 0; c < 16; ++c) {
      u16x4 u;
      u[0] = f2bf(v.x); u[1] = f2bf(v.y); u[2] = f2bf(v.z); u[3] = f2bf(v.w);
      *(u16x4*)(stage + xr * 128 + ((kp4 << 1) ^ ((xr & 7) << 4))) = u;
      __syncthreads();
      if (c < 15)                          // T14: next chunk's x load early
        v = *(const float4*)(xs + (size_t)xr * 1024 + (c + 1) * 64 + kp4);
      #pragma unroll
      for (int ks = 0; ks < 2; ++ks) {
        bf16x8 b0 = *(const bf16x8*)(q0 + c * 64 + ks * 32);
        bf16x8 b1 = *(const bf16x8*)(q1 + c * 64 + ks * 32);
        bf16x8 b2 = *(const bf16x8*)(q2 + c * 64 + ks * 32);
        bf16x8 b3 = *(const bf16x8*)(q3 + c * 64 + ks * 32);
        const int kb = ((ks << 6) | kg2) ^ sw;
        bf16x8 a0 = *(const bf16x8*)(stage + r16 * 128 + kb);
        bf16x8 a1 = *(const bf16x8*)(stage + (16 + r16) * 128 + kb);
        __builtin_amdgcn_s_setprio(1);
        acc[0][0] = MFMA(a0, b0, acc[0][0]); acc[0][1] = MFMA(a0, b1, acc[0][1]);
        acc[0][2] = MFMA(a0, b2, acc[0][2]); acc[0][3] = MFMA(a0, b3, acc[0][3]);
        acc[1][0] = MFMA(a1, b0, acc[1][0]); acc[1][1] = MFMA(a1, b1, acc[1][1]);
        acc[1][2] = MFMA(a1, b2, acc[1][2]); acc[1][3] = MFMA(a1, b3, acc[1][3]);
        __builtin_amdgcn_s_setprio(0);
      }
      __syncthreads();
    }
    char* z_ = smem + Z_OFF;
    #pragma unroll
    for (int nt = 0; nt < 4; ++nt) {
      const int col = c0 + nt * 16 + r16;
      const float bb = enc_b1[col];
      #pragma unroll
      for (int mt = 0; mt < 2; ++mt) {
        #pragma unroll
        for (int r = 0; r < 4; ++r) {
          const int row = mt * 16 + ((lane >> 4) << 2) + r;
          *(u16*)(z_ + row * 1024 + ((col << 1) ^ ((row & 7) << 4))) =
              f2bf(gelu_f(acc[mt][nt][r] + bb));
        }
      }
    }
  }

  // ===== enc2 / enc3 (in-place) =====
  gemm512<0>(smem, wE2, enc_b2, nullptr, 0, m0);
  gemm512<1>(smem, wE3, enc_b3, nullptr, 0, m0);

  // ===== 4 latent layers =====
  #pragma unroll 1
  for (int l = 0; l < 4; ++l) {
    norm_phase(smem, mlp1_w + l * 1024, mlp1_b + l * 64,
               mlp2_w + l * 4096, mlp2_b + l * 64,
               mlp3_w + l * 1024, gate_b + l * 16);
    gemm512<2>(smem, wMix + (size_t)l * 262144, nullptr, nullptr, 0, m0);
  }

  // ===== decoder =====
  gemm512<0>(smem, wD1, dec_b1, nullptr, 0, m0);
  gemm512<0>(smem, wD2, dec_b2, nullptr, 0, m0);
  gemm512<3>(smem, wD3, dec_b3, out, 0, m0);
  gemm512<3>(smem, wD3, dec_b3, out, 512, m0);
}

// ---------------- launch ----------------
extern "C" void kernel_launch(void* const* d_in, const int* in_sizes, int n_in,
                              void* d_out, int out_size, void* d_ws, size_t ws_size,
                              hipStream_t stream)
{
  (void)in_sizes; (void)n_in; (void)out_size; (void)ws_size;
  const float* x      = (const float*)d_in[0];
  const float* enc_w1 = (const float*)d_in[1];
  const float* enc_b1 = (const float*)d_in[2];
  const float* enc_w2 = (const float*)d_in[3];
  const float* enc_b2 = (const float*)d_in[4];
  const float* enc_w3 = (const float*)d_in[5];
  const float* enc_b3 = (const float*)d_in[6];
  const float* mlp1_w = (const float*)d_in[7];
  const float* mlp1_b = (const float*)d_in[8];
  const float* mlp2_w = (const float*)d_in[9];
  const float* mlp2_b = (const float*)d_in[10];
  const float* mlp3_w = (const float*)d_in[11];
  const float* mix_w  = (const float*)d_in[12];
  const float* gate_b = (const float*)d_in[13];
  const float* dec_w1 = (const float*)d_in[14];
  const float* dec_b1 = (const float*)d_in[15];
  const float* dec_w2 = (const float*)d_in[16];
  const float* dec_b2 = (const float*)d_in[17];
  const float* dec_w3 = (const float*)d_in[18];
  const float* dec_b3 = (const float*)d_in[19];

  u16* wBase = (u16*)d_ws;
  u16* wE1 = wBase;
  u16* wE2 = wE1 + 524288;
  u16* wE3 = wE2 + 262144;
  u16* wD1 = wE3 + 262144;
  u16* wD2 = wD1 + 262144;
  u16* wD3 = wD2 + 262144;
  u16* wMix = wD3 + 524288;

  cvt_all<<<512, 256, 0, stream>>>(enc_w1, enc_w2, enc_w3, dec_w1, dec_w2, dec_w3,
                                   mix_w, wBase);

  ugn_mega<<<2048, 512, SMEM_BYTES, stream>>>(
      x, enc_b1, enc_b2, enc_b3, mlp1_w, mlp1_b, mlp2_w, mlp2_b, mlp3_w, gate_b,
      dec_b1, dec_b2, dec_b3, wE1, wE2, wE3, wMix, wD1, wD2, wD3, (float*)d_out);
}

// Round 10
// 1698.609 us; speedup vs baseline: 1.2053x; 1.2053x over previous
//
#include <hip/hip_runtime.h>
#include <hip/hip_bf16.h>

typedef float f32x4 __attribute__((ext_vector_type(4)));
typedef __bf16 bf16x8 __attribute__((ext_vector_type(8)));
typedef unsigned short u16x8 __attribute__((ext_vector_type(8)));
typedef unsigned short u16;

__device__ __forceinline__ u16 f2bf(float f) {
  __bf16 h = (__bf16)f;                       // native cvt (RNE)
  return __builtin_bit_cast(u16, h);
}
__device__ __forceinline__ float bf2f(u16 s) {
  return __uint_as_float(((unsigned int)s) << 16);
}
__device__ __forceinline__ float gelu_f(float x) {
  return 0.5f * x * (1.0f + erff(x * 0.70710678118654752f)); // erf GELU
}
__device__ __forceinline__ void gload_lds16(const void* g, void* l) {
  __builtin_amdgcn_global_load_lds((const __attribute__((address_space(1))) void*)g,
                                   (__attribute__((address_space(3))) void*)l, 16, 0, 0);
}
#define MFMA(a, b, c) __builtin_amdgcn_mfma_f32_16x16x32_bf16((a), (b), (c), 0, 0, 0)

// ---------------- merged weight conversion ----------------
__global__ void cvt_all(const float* __restrict__ e1, const float* __restrict__ e2,
                        const float* __restrict__ e3, const float* __restrict__ d1,
                        const float* __restrict__ d2, const float* __restrict__ d3,
                        const float* __restrict__ mx, u16* __restrict__ dst)
{
  int i = blockIdx.x * blockDim.x + threadIdx.x;
  int stride = gridDim.x * blockDim.x;
  for (; i < 3145728; i += stride) {
    float v;
    if (i < 524288)        v = e1[i];
    else if (i < 786432)   v = e2[i - 524288];
    else if (i < 1048576)  v = e3[i - 786432];
    else if (i < 1310720)  v = d1[i - 1048576];
    else if (i < 1572864)  v = d2[i - 1310720];
    else if (i < 2097152)  v = d3[i - 1572864];
    else {
      // mix_w [L,16,16,32,32] (l,bi,j,e,d) -> W[l][o=bi*32+e][k=j*32+d]
      int j = i - 2097152;
      int l = j >> 18, rem = j & 262143;
      int o = rem >> 9, k = rem & 511;
      int bi = o >> 5, e = o & 31, jj = k >> 5, dd = k & 31;
      v = mx[(((l * 16 + bi) * 16 + jj) * 32 + e) * 32 + dd];
    }
    dst[i] = f2bf(v);
  }
}

// ---------------- GEMM: C = A * W^T (+epilogue), 2-phase dbuf, BM=128 BN=64 ----------------
// 4 waves as 2(M)x2(N); wave tile 64x32; acc[4][2]=32 VGPR -> ~85 live, no spill @(256,2).
// LDS 48KB -> 3 blocks/CU (12 waves/CU). XCD panel swizzle: 8..16 blocks sharing an
// A-panel are consecutive on one XCD -> panel L2-resident, A fetched once from HBM.
// EPI: 0 bias+GELU->bf16 ; 1 bias->bf16 ; 2 latent combine->bf16 ; 3 bias->f32
template<int EPI, bool AF32>
__global__ __launch_bounds__(256, 2)
void gemm_bt(const void* __restrict__ Ap, const u16* __restrict__ Bw,
             const float* __restrict__ bias, void* __restrict__ Cp,
             const u16* __restrict__ zOld, const float* __restrict__ scales,
             const float* __restrict__ gateBias, int M, int N, int K)
{
  constexpr int BK = 64;
  __shared__ u16 At[2][128 * BK];   // 16KB each
  __shared__ u16 Bt[2][64 * BK];    // 8KB each
  const int tid = threadIdx.x;
  const int lane = tid & 63;
  const int wid = tid >> 6;

  // XCD-aware swizzle (ny % 8 == 0 always here)
  const int nx = N >> 6;               // N-tiles (BN=64)
  const int ny = M >> 7;               // M-panels (BM=128)
  const int d = blockIdx.x;
  const int xcd = d & 7;
  const int seq = d >> 3;
  const int by = xcd * (ny >> 3) + seq / nx;
  const int bx = seq - (seq / nx) * nx;
  const int m0 = by << 7;
  const int n0 = bx << 6;

  const int wr = wid >> 1, wc = wid & 1;   // wave tile 64x32
  const int r16 = lane & 15;
  const int kg = (lane >> 4) << 3;         // k elem offset 0,8,16,24
  const int sw = (r16 & 7) << 4;           // XOR swizzle

  const int NT = K >> 6;
  f32x4 acc[4][2] = {};
  float4 aA[8];                            // AF32 staging regs

  const float* Af = (const float*)Ap;
  const u16*   Ab = (const u16*)Ap;

  // ---- prologue: stage tile 0 into buf 0 ----
  if constexpr (AF32) {
    #pragma unroll
    for (int it = 0; it < 4; ++it) {
      int c = it * 256 + tid;              // 1024 chunks (A: 128x64 bf16 dest)
      int row = c >> 3;
      int cb = (c & 7) << 4;
      const float* src = Af + (size_t)(m0 + row) * K + ((c & 7) << 3);
      float4 v0 = *(const float4*)src;
      float4 v1 = *(const float4*)(src + 4);
      u16x8 u;
      u[0] = f2bf(v0.x); u[1] = f2bf(v0.y); u[2] = f2bf(v0.z); u[3] = f2bf(v0.w);
      u[4] = f2bf(v1.x); u[5] = f2bf(v1.y); u[6] = f2bf(v1.z); u[7] = f2bf(v1.w);
      *(u16x8*)((char*)At[0] + row * 128 + (cb ^ ((row & 7) << 4))) = u;
    }
  } else {
    #pragma unroll
    for (int it = 0; it < 4; ++it) {
      int c = ((it * 4 + wid) << 6) + lane;
      int row = c >> 3;
      int cb = (c & 7) << 4;
      const char* g = (const char*)(Ab + (size_t)(m0 + row) * K) + (cb ^ ((row & 7) << 4));
      gload_lds16(g, (char*)At[0] + ((it * 4 + wid) << 10));
    }
  }
  #pragma unroll
  for (int it = 0; it < 2; ++it) {
    int c = ((it * 4 + wid) << 6) + lane;  // 512 chunks (B: 64x64)
    int row = c >> 3;
    int cb = (c & 7) << 4;
    const char* g = (const char*)(Bw + (size_t)(n0 + row) * K) + (cb ^ ((row & 7) << 4));
    gload_lds16(g, (char*)Bt[0] + ((it * 4 + wid) << 10));
  }
  __syncthreads();

  // ---- main loop: issue next staging first, compute, ONE barrier ----
  for (int kt = 0; kt < NT; ++kt) {
    const int cur = kt & 1;
    const bool hasNext = (kt + 1) < NT;

    if (hasNext) {
      const int kn = (kt + 1) << 6;
      if constexpr (AF32) {
        #pragma unroll
        for (int it = 0; it < 4; ++it) {
          int c = it * 256 + tid;
          int row = c >> 3;
          const float* src = Af + (size_t)(m0 + row) * K + kn + ((c & 7) << 3);
          aA[it * 2]     = *(const float4*)src;
          aA[it * 2 + 1] = *(const float4*)(src + 4);
        }
      } else {
        #pragma unroll
        for (int it = 0; it < 4; ++it) {
          int c = ((it * 4 + wid) << 6) + lane;
          int row = c >> 3;
          int cb = (c & 7) << 4;
          const char* g = (const char*)(Ab + (size_t)(m0 + row) * K + kn) + (cb ^ ((row & 7) << 4));
          gload_lds16(g, (char*)At[cur ^ 1] + ((it * 4 + wid) << 10));
        }
      }
      #pragma unroll
      for (int it = 0; it < 2; ++it) {
        int c = ((it * 4 + wid) << 6) + lane;
        int row = c >> 3;
        int cb = (c & 7) << 4;
        const char* g = (const char*)(Bw + (size_t)(n0 + row) * K + kn) + (cb ^ ((row & 7) << 4));
        gload_lds16(g, (char*)Bt[cur ^ 1] + ((it * 4 + wid) << 10));
      }
    }

    // compute current tile
    #pragma unroll
    for (int kk = 0; kk < BK; kk += 32) {
      const int kb = ((kk + kg) << 1) ^ sw;
      bf16x8 av[4], bv[2];
      #pragma unroll
      for (int m = 0; m < 4; ++m)
        av[m] = *(const bf16x8*)((const char*)At[cur] + (wr * 64 + m * 16 + r16) * 128 + kb);
      #pragma unroll
      for (int n = 0; n < 2; ++n)
        bv[n] = *(const bf16x8*)((const char*)Bt[cur] + (wc * 32 + n * 16 + r16) * 128 + kb);
      __builtin_amdgcn_s_setprio(1);
      #pragma unroll
      for (int m = 0; m < 4; ++m)
        #pragma unroll
        for (int n = 0; n < 2; ++n)
          acc[m][n] = MFMA(av[m], bv[n], acc[m][n]);
      __builtin_amdgcn_s_setprio(0);
    }

    if (hasNext) {
      if constexpr (AF32) {
        #pragma unroll
        for (int it = 0; it < 4; ++it) {
          int c = it * 256 + tid;
          int row = c >> 3;
          int cb = (c & 7) << 4;
          float4 v0 = aA[it * 2], v1 = aA[it * 2 + 1];
          u16x8 u;
          u[0] = f2bf(v0.x); u[1] = f2bf(v0.y); u[2] = f2bf(v0.z); u[3] = f2bf(v0.w);
          u[4] = f2bf(v1.x); u[5] = f2bf(v1.y); u[6] = f2bf(v1.z); u[7] = f2bf(v1.w);
          *(u16x8*)((char*)At[cur ^ 1] + row * 128 + (cb ^ ((row & 7) << 4))) = u;
        }
      }
    }
    __syncthreads();
  }

  // ---- epilogue ----  D: col = lane&15, row = (lane>>4)*4 + reg
  const int colBase = n0 + wc * 32 + r16;
  const int rowBase = m0 + wr * 64 + ((lane >> 4) << 2);
  #pragma unroll
  for (int n = 0; n < 2; ++n) {
    int col = colBase + n * 16;
    float bv_ = 0.f, gate = 0.f;
    if constexpr (EPI == 0 || EPI == 1 || EPI == 3) bv_ = bias[col];
    if constexpr (EPI == 2) gate = 1.f / (1.f + expf(-gateBias[col >> 5]));
    #pragma unroll
    for (int m = 0; m < 4; ++m) {
      #pragma unroll
      for (int r = 0; r < 4; ++r) {
        int row = rowBase + m * 16 + r;
        float v = acc[m][n][r];
        if constexpr (EPI == 0) {
          ((u16*)Cp)[(size_t)row * N + col] = f2bf(gelu_f(v + bv_));
        } else if constexpr (EPI == 1) {
          ((u16*)Cp)[(size_t)row * N + col] = f2bf(v + bv_);
        } else if constexpr (EPI == 2) {
          float sc = scales[(size_t)row * 16 + (col >> 5)];
          float zo = bf2f(zOld[(size_t)row * 512 + col]);
          ((u16*)Cp)[(size_t)row * N + col] = f2bf(zo * (1.f + sc) + gate * v);
        } else {
          ((float*)Cp)[(size_t)row * N + col] = v + bv_;
        }
      }
    }
  }
}

// ---------------- per-row bundle-norm MLP -> scales ----------------
__global__ __launch_bounds__(256)
void norm_mlp(const u16* __restrict__ z,
              const float* __restrict__ w1, const float* __restrict__ b1,
              const float* __restrict__ w2, const float* __restrict__ b2,
              const float* __restrict__ w3, float* __restrict__ scales, int Mrows)
{
  const int lane = threadIdx.x & 63;
  const int wv = threadIdx.x >> 6;
  for (int row = blockIdx.x * 4 + wv; row < Mrows; row += gridDim.x * 4) {
    u16x8 zv = *(const u16x8*)(z + (size_t)row * 512 + lane * 8);
    float ss = 0.f;
    #pragma unroll
    for (int j = 0; j < 8; ++j) { float f = bf2f(zv[j]); ss += f * f; }
    ss += __shfl_xor(ss, 1);
    ss += __shfl_xor(ss, 2);                 // 4-lane group = one 32-elem bundle
    float nrm = sqrtf(ss) + 1e-8f;
    float h1 = b1[lane];
    #pragma unroll
    for (int i = 0; i < 16; ++i) h1 += __shfl(nrm, i * 4) * w1[lane * 16 + i];
    h1 = gelu_f(h1);
    float h2 = b2[lane];
    #pragma unroll
    for (int k = 0; k < 64; ++k) h2 += __shfl(h1, k) * w2[lane * 64 + k];
    h2 = gelu_f(h2);
    float s = 0.f;
    const int i16 = lane & 15;
    #pragma unroll
    for (int k = 0; k < 64; ++k) s += __shfl(h2, k) * w3[i16 * 64 + k];
    if (lane < 16) {
      s = (s > 20.f) ? s : log1pf(expf(s));  // softplus
      scales[(size_t)row * 16 + lane] = s;
    }
  }
}

// ---------------- launch ----------------
extern "C" void kernel_launch(void* const* d_in, const int* in_sizes, int n_in,
                              void* d_out, int out_size, void* d_ws, size_t ws_size,
                              hipStream_t stream)
{
  (void)in_sizes; (void)n_in; (void)out_size; (void)ws_size;
  const float* x      = (const float*)d_in[0];
  const float* enc_w1 = (const float*)d_in[1];
  const float* enc_b1 = (const float*)d_in[2];
  const float* enc_w2 = (const float*)d_in[3];
  const float* enc_b2 = (const float*)d_in[4];
  const float* enc_w3 = (const float*)d_in[5];
  const float* enc_b3 = (const float*)d_in[6];
  const float* mlp1_w = (const float*)d_in[7];
  const float* mlp1_b = (const float*)d_in[8];
  const float* mlp2_w = (const float*)d_in[9];
  const float* mlp2_b = (const float*)d_in[10];
  const float* mlp3_w = (const float*)d_in[11];
  const float* mix_w  = (const float*)d_in[12];
  const float* gate_b = (const float*)d_in[13];
  const float* dec_w1 = (const float*)d_in[14];
  const float* dec_b1 = (const float*)d_in[15];
  const float* dec_w2 = (const float*)d_in[16];
  const float* dec_b2 = (const float*)d_in[17];
  const float* dec_w3 = (const float*)d_in[18];
  const float* dec_b3 = (const float*)d_in[19];

  char* ws = (char*)d_ws;
  u16*   zA     = (u16*)ws;                            // 64 MB
  u16*   zB     = (u16*)(ws + (size_t)(64u << 20));    // 64 MB
  float* scales = (float*)(ws + (size_t)(128u << 20)); // 4 MB
  u16*   wBase  = (u16*)(ws + (size_t)(132u << 20));
  u16*   wE1    = wBase;
  u16*   wE2    = wE1 + 524288;
  u16*   wE3    = wE2 + 262144;
  u16*   wD1    = wE3 + 262144;
  u16*   wD2    = wD1 + 262144;
  u16*   wD3    = wD2 + 262144;
  u16*   wMix   = wD3 + 524288;                        // 4 x 512 x 512

  cvt_all<<<512, 256, 0, stream>>>(enc_w1, enc_w2, enc_w3, dec_w1, dec_w2, dec_w3,
                                   mix_w, wBase);

  const int M = 65536;
  dim3 blk(256);
  const int g512  = 8  * 512;   // (N/64) * (M/128), 1-D XCD-swizzled
  const int g1024 = 16 * 512;

  // encoder
  gemm_bt<0, true ><<<g512, blk, 0, stream>>>(x,  wE1, enc_b1, zA, nullptr, nullptr, nullptr, M, 512, 1024);
  gemm_bt<0, false><<<g512, blk, 0, stream>>>(zA, wE2, enc_b2, zB, nullptr, nullptr, nullptr, M, 512, 512);
  gemm_bt<1, false><<<g512, blk, 0, stream>>>(zB, wE3, enc_b3, zA, nullptr, nullptr, nullptr, M, 512, 512);

  // latent layers
  u16* cur = zA;
  u16* nxt = zB;
  for (int l = 0; l < 4; ++l) {
    norm_mlp<<<4096, dim3(256), 0, stream>>>(cur, mlp1_w + l * 1024, mlp1_b + l * 64,
                                             mlp2_w + l * 4096, mlp2_b + l * 64,
                                             mlp3_w + l * 1024, scales, M);
    gemm_bt<2, false><<<g512, blk, 0, stream>>>(cur, wMix + (size_t)l * 262144, nullptr, nxt,
                                                cur, scales, gate_b + l * 16, M, 512, 512);
    u16* t = cur; cur = nxt; nxt = t;
  }

  // decoder
  gemm_bt<0, false><<<g512, blk, 0, stream>>>(cur, wD1, dec_b1, nxt, nullptr, nullptr, nullptr, M, 512, 512);
  { u16* t = cur; cur = nxt; nxt = t; }
  gemm_bt<0, false><<<g512, blk, 0, stream>>>(cur, wD2, dec_b2, nxt, nullptr, nullptr, nullptr, M, 512, 512);
  { u16* t = cur; cur = nxt; nxt = t; }
  gemm_bt<3, false><<<g1024, blk, 0, stream>>>(cur, wD3, dec_b3, d_out, nullptr, nullptr, nullptr, M, 1024, 512);
}